// Round 1
// baseline (205.678 us; speedup 1.0000x reference)
//
#include <hip/hip_runtime.h>
#include <hip/hip_bf16.h>
#include <math.h>

typedef __bf16 bhalf;
typedef __bf16 bhalf8 __attribute__((ext_vector_type(8)));
typedef float floatx4 __attribute__((ext_vector_type(4)));

#define MFMA_BF16(A, B, C) __builtin_amdgcn_mfma_f32_16x16x32_bf16((A), (B), (C), 0, 0, 0)

// ---------------- convert x: fp32 -> bf16 ----------------
__global__ __launch_bounds__(256) void cvt_x_kernel(const float* __restrict__ in,
                                                    bhalf* __restrict__ out) {
  int i = (blockIdx.x * 256 + threadIdx.x) * 8;
  floatx4 v0 = *(const floatx4*)(in + i);
  floatx4 v1 = *(const floatx4*)(in + i + 4);
  bhalf8 o;
  o[0] = (bhalf)v0[0]; o[1] = (bhalf)v0[1]; o[2] = (bhalf)v0[2]; o[3] = (bhalf)v0[3];
  o[4] = (bhalf)v1[0]; o[5] = (bhalf)v1[1]; o[6] = (bhalf)v1[2]; o[7] = (bhalf)v1[3];
  *(bhalf8*)(out + i) = o;
}

// ---------------- transpose + convert: [R][C] fp32 -> [C][R] bf16 ----------------
__global__ __launch_bounds__(256) void transpose_bf_kernel(const float* __restrict__ in,
                                                           bhalf* __restrict__ out,
                                                           int R, int C) {
  __shared__ float tile[32][33];
  int c0 = blockIdx.x * 32, r0 = blockIdx.y * 32;
  int tx = threadIdx.x, ty = threadIdx.y;
#pragma unroll
  for (int i = 0; i < 32; i += 8)
    tile[ty + i][tx] = in[(size_t)(r0 + ty + i) * C + c0 + tx];
  __syncthreads();
#pragma unroll
  for (int i = 0; i < 32; i += 8)
    out[(size_t)(c0 + ty + i) * R + r0 + tx] = (bhalf)tile[tx][ty + i];
}

// ---------------- GEMM: C[M,N] = A[M,K] * BT[N,K]^T  (bf16 in, fp32 acc) --------
// EPI=0: plain fp32 store to Cout.  EPI=1: RoPE + scatter to q/k/v [b,h,s,d] bf16.
template <int EPI>
__global__ __launch_bounds__(256, 2) void gemm_bt_kernel(
    const bhalf* __restrict__ A, const bhalf* __restrict__ BT, float* __restrict__ Cout,
    bhalf* __restrict__ qb, bhalf* __restrict__ kb, bhalf* __restrict__ vb,
    int M, int N, int K) {
  __shared__ __attribute__((aligned(16))) bhalf As[128 * 40];  // pad 32->40 elems
  __shared__ __attribute__((aligned(16))) bhalf Bs[128 * 40];
  const int tid = threadIdx.x;
  const int lane = tid & 63;
  const int w = tid >> 6, wr = w >> 1, wc = w & 1;
  const int m0 = blockIdx.y * 128, n0 = blockIdx.x * 128;
  const int l15 = lane & 15, lhi = lane >> 4;

  floatx4 acc[4][4];
#pragma unroll
  for (int i = 0; i < 4; ++i)
#pragma unroll
    for (int j = 0; j < 4; ++j) acc[i][j] = (floatx4){0.f, 0.f, 0.f, 0.f};

  const int srow = tid >> 1;           // 0..127
  const int skc = (tid & 1) * 16;      // 0 or 16
  const bhalf* aptr = A + (size_t)(m0 + srow) * K + skc;
  const bhalf* bptr = BT + (size_t)(n0 + srow) * K + skc;
  bhalf* asd = &As[srow * 40 + skc];
  bhalf* bsd = &Bs[srow * 40 + skc];

  for (int k0 = 0; k0 < K; k0 += 32) {
    bhalf8 ra0 = *(const bhalf8*)(aptr + k0);
    bhalf8 ra1 = *(const bhalf8*)(aptr + k0 + 8);
    bhalf8 rb0 = *(const bhalf8*)(bptr + k0);
    bhalf8 rb1 = *(const bhalf8*)(bptr + k0 + 8);
    __syncthreads();
    *(bhalf8*)asd = ra0;
    *(bhalf8*)(asd + 8) = ra1;
    *(bhalf8*)bsd = rb0;
    *(bhalf8*)(bsd + 8) = rb1;
    __syncthreads();
    bhalf8 af[4], bf[4];
#pragma unroll
    for (int mt = 0; mt < 4; ++mt)
      af[mt] = *(const bhalf8*)&As[(wr * 64 + mt * 16 + l15) * 40 + lhi * 8];
#pragma unroll
    for (int nt = 0; nt < 4; ++nt)
      bf[nt] = *(const bhalf8*)&Bs[(wc * 64 + nt * 16 + l15) * 40 + lhi * 8];
#pragma unroll
    for (int mt = 0; mt < 4; ++mt)
#pragma unroll
      for (int nt = 0; nt < 4; ++nt)
        acc[mt][nt] = MFMA_BF16(af[mt], bf[nt], acc[mt][nt]);
  }

  // epilogue: C layout col=lane&15, row=(lane>>4)*4+reg
#pragma unroll
  for (int mt = 0; mt < 4; ++mt) {
#pragma unroll
    for (int nt = 0; nt < 4; ++nt) {
#pragma unroll
      for (int r = 0; r < 4; ++r) {
        float val = acc[mt][nt][r];
        int mg = m0 + wr * 64 + mt * 16 + lhi * 4 + r;
        int ng = n0 + wc * 64 + nt * 16 + l15;
        if (EPI == 0) {
          Cout[(size_t)mg * N + ng] = val;
        } else {
          int b = mg >> 11, s = mg & 2047;
          int sel = ng >> 10, nn = ng & 1023;
          int h = nn >> 6, d = nn & 63;
          float partner = __shfl_xor(val, 1, 64);  // pair column d^1 lives in lane^1
          if (sel < 2) {
            int t2 = d >> 1;
            // inv_freq = 10000^(-t/32) = 2^(-t*log2(10000)/32)
            float inv = exp2f((float)t2 * -0.4152410118609203f);
            float ang = (float)s * inv;
            float sn, cs;
            sincosf(ang, &sn, &cs);
            val = (d & 1) ? fmaf(val, cs, partner * sn) : fmaf(val, cs, -partner * sn);
          }
          bhalf bv = (bhalf)val;
          bhalf* dst = (sel == 0) ? qb : ((sel == 1) ? kb : vb);
          dst[((size_t)((b << 4) + h) * 2048 + s) * 64 + d] = bv;
        }
      }
    }
  }
}

// ---------------- flash sliding-window attention ----------------
// grid (S/64, B*H). block 256 = 4 waves, wave w owns q rows [q0+16w, q0+16w+15].
__global__ __launch_bounds__(256, 2) void attn_kernel(const bhalf* __restrict__ q,
                                                      const bhalf* __restrict__ k,
                                                      const bhalf* __restrict__ v,
                                                      bhalf* __restrict__ attn_out) {
  __shared__ __attribute__((aligned(16))) bhalf Qs[64 * 72];
  __shared__ __attribute__((aligned(16))) bhalf Ks[64 * 72];
  __shared__ __attribute__((aligned(16))) bhalf Vt[64 * 72];      // [d][kv] transposed
  __shared__ __attribute__((aligned(16))) bhalf Ps[4][16 * 72];   // per-wave P buffer

  const int bx = blockIdx.x;   // q tile
  const int bh = blockIdx.y;   // b*16+h
  const int tid = threadIdx.x, lane = tid & 63, w = tid >> 6;
  const int l15 = lane & 15, lhi = lane >> 4;
  const int q0 = bx * 64;
  const size_t base = (size_t)bh * 2048 * 64;
  const int sr = tid >> 2, sc = (tid & 3) * 16;

  {
    const bhalf* src = q + base + (size_t)(q0 + sr) * 64 + sc;
    *(bhalf8*)&Qs[sr * 72 + sc] = *(const bhalf8*)src;
    *(bhalf8*)&Qs[sr * 72 + sc + 8] = *(const bhalf8*)(src + 8);
  }

  floatx4 O[4];
#pragma unroll
  for (int dt = 0; dt < 4; ++dt) O[dt] = (floatx4){0.f, 0.f, 0.f, 0.f};
  float m_i[4], l_i[4];
#pragma unroll
  for (int r = 0; r < 4; ++r) { m_i[r] = -1e30f; l_i[r] = 0.f; }

  const int iRow = q0 + w * 16 + lhi * 4;  // + r = global query index

  int kt0 = bx - 8;
  if (kt0 < 0) kt0 = 0;
  for (int kt = kt0; kt <= bx; ++kt) {
    __syncthreads();
    {
      const bhalf* ksrc = k + base + (size_t)(kt * 64 + sr) * 64 + sc;
      *(bhalf8*)&Ks[sr * 72 + sc] = *(const bhalf8*)ksrc;
      *(bhalf8*)&Ks[sr * 72 + sc + 8] = *(const bhalf8*)(ksrc + 8);
      const bhalf* vsrc = v + base + (size_t)(kt * 64 + sr) * 64 + sc;
      bhalf8 va = *(const bhalf8*)vsrc;
      bhalf8 vbv = *(const bhalf8*)(vsrc + 8);
#pragma unroll
      for (int j = 0; j < 8; ++j) Vt[(sc + j) * 72 + sr] = va[j];
#pragma unroll
      for (int j = 0; j < 8; ++j) Vt[(sc + 8 + j) * 72 + sr] = vbv[j];
    }
    __syncthreads();

    bhalf8 qa0 = *(const bhalf8*)&Qs[(w * 16 + l15) * 72 + lhi * 8];
    bhalf8 qa1 = *(const bhalf8*)&Qs[(w * 16 + l15) * 72 + 32 + lhi * 8];
    floatx4 sf[4];
#pragma unroll
    for (int nt = 0; nt < 4; ++nt) {
      bhalf8 kb0 = *(const bhalf8*)&Ks[(nt * 16 + l15) * 72 + lhi * 8];
      bhalf8 kb1 = *(const bhalf8*)&Ks[(nt * 16 + l15) * 72 + 32 + lhi * 8];
      floatx4 sacc = (floatx4){0.f, 0.f, 0.f, 0.f};
      sacc = MFMA_BF16(qa0, kb0, sacc);
      sacc = MFMA_BF16(qa1, kb1, sacc);
      sf[nt] = sacc;
    }
    // mask + scale (scores layout: row=(lane>>4)*4+r, col=lane&15)
#pragma unroll
    for (int nt = 0; nt < 4; ++nt) {
      int j = kt * 64 + nt * 16 + l15;
#pragma unroll
      for (int r = 0; r < 4; ++r) {
        int i = iRow + r;
        bool ok = (j <= i) && (j + 512 >= i);
        sf[nt][r] = ok ? sf[nt][r] * 0.125f : -1e30f;
      }
    }
    float alpha[4];
#pragma unroll
    for (int r = 0; r < 4; ++r) {
      float mx = fmaxf(fmaxf(sf[0][r], sf[1][r]), fmaxf(sf[2][r], sf[3][r]));
      mx = fmaxf(mx, __shfl_xor(mx, 1, 64));
      mx = fmaxf(mx, __shfl_xor(mx, 2, 64));
      mx = fmaxf(mx, __shfl_xor(mx, 4, 64));
      mx = fmaxf(mx, __shfl_xor(mx, 8, 64));
      float mnew = fmaxf(m_i[r], mx);
      alpha[r] = exp2f((m_i[r] - mnew) * 1.44269504f);
      m_i[r] = mnew;
    }
    float rs[4] = {0.f, 0.f, 0.f, 0.f};
#pragma unroll
    for (int nt = 0; nt < 4; ++nt) {
#pragma unroll
      for (int r = 0; r < 4; ++r) {
        float p = exp2f((sf[nt][r] - m_i[r]) * 1.44269504f);
        rs[r] += p;
        Ps[w][(lhi * 4 + r) * 72 + nt * 16 + l15] = (bhalf)p;
      }
    }
#pragma unroll
    for (int r = 0; r < 4; ++r) {
      float t = rs[r];
      t += __shfl_xor(t, 1, 64);
      t += __shfl_xor(t, 2, 64);
      t += __shfl_xor(t, 4, 64);
      t += __shfl_xor(t, 8, 64);
      l_i[r] = l_i[r] * alpha[r] + t;
    }
#pragma unroll
    for (int dt = 0; dt < 4; ++dt)
#pragma unroll
      for (int r = 0; r < 4; ++r) O[dt][r] *= alpha[r];
    // P (A-layout via LDS round-trip) @ V (B^T = Vt rows)
#pragma unroll
    for (int ks = 0; ks < 2; ++ks) {
      bhalf8 pa = *(const bhalf8*)&Ps[w][l15 * 72 + ks * 32 + lhi * 8];
#pragma unroll
      for (int dt = 0; dt < 4; ++dt) {
        bhalf8 vfr = *(const bhalf8*)&Vt[(dt * 16 + l15) * 72 + ks * 32 + lhi * 8];
        O[dt] = MFMA_BF16(pa, vfr, O[dt]);
      }
    }
  }

  const int b = bh >> 4, h = bh & 15;
#pragma unroll
  for (int dt = 0; dt < 4; ++dt) {
#pragma unroll
    for (int r = 0; r < 4; ++r) {
      float val = O[dt][r] / l_i[r];
      int s = q0 + w * 16 + lhi * 4 + r;
      attn_out[((size_t)(b * 2048 + s)) * 1024 + h * 64 + dt * 16 + l15] = (bhalf)val;
    }
  }
}

// ---------------- host launch ----------------
extern "C" void kernel_launch(void* const* d_in, const int* in_sizes, int n_in,
                              void* d_out, int out_size, void* d_ws, size_t ws_size,
                              hipStream_t stream) {
  (void)in_sizes; (void)n_in; (void)out_size; (void)ws_size;
  const float* x = (const float*)d_in[0];
  const float* w_qkv = (const float*)d_in[1];
  const float* w_o = (const float*)d_in[2];
  float* out = (float*)d_out;
  char* ws = (char*)d_ws;

  bhalf* x_bf  = (bhalf*)(ws);                         // 8 MB
  bhalf* wqkvT = (bhalf*)(ws + ((size_t)8 << 20));     // 6 MB
  bhalf* woT   = (bhalf*)(ws + ((size_t)14 << 20));    // 2 MB
  bhalf* qb    = (bhalf*)(ws + ((size_t)16 << 20));    // 8 MB
  bhalf* kb    = (bhalf*)(ws + ((size_t)24 << 20));    // 8 MB
  bhalf* vb    = (bhalf*)(ws + ((size_t)32 << 20));    // 8 MB
  bhalf* attn  = (bhalf*)(ws + ((size_t)40 << 20));    // 8 MB

  cvt_x_kernel<<<2048, 256, 0, stream>>>(x, x_bf);
  transpose_bf_kernel<<<dim3(96, 32), dim3(32, 8), 0, stream>>>(w_qkv, wqkvT, 1024, 3072);
  transpose_bf_kernel<<<dim3(32, 32), dim3(32, 8), 0, stream>>>(w_o, woT, 1024, 1024);
  gemm_bt_kernel<1><<<dim3(24, 32), 256, 0, stream>>>(x_bf, wqkvT, nullptr, qb, kb, vb,
                                                      4096, 3072, 1024);
  attn_kernel<<<dim3(32, 32), 256, 0, stream>>>(qb, kb, vb, attn);
  gemm_bt_kernel<0><<<dim3(8, 32), 256, 0, stream>>>(attn, woT, out, nullptr, nullptr, nullptr,
                                                     4096, 1024, 1024);
}